// Round 15
// baseline (2329.395 us; speedup 1.0000x reference)
//
#include <hip/hip_runtime.h>
#include <hip/hip_fp16.h>

// LSTM: B=256, S=4096, D=64, H=128 (4H=512 gate cols [i|f|g|o]), K=192=[h;x].
// One batch element per block (256 blocks = 1/CU), 256 threads = 4 waves
// (1 wave/SIMD). z = [h;x] @ [Wh;Wi] via v_mfma_f32_16x16x32_f16, A rows 0+4
// carry the batch row (lanes 0-31 own one unit's gates).
// Schedule per step (R14 + combine interleaved into the kk3 MFMA block):
//   1. ds_read Ah (h_s) + next-x frags (x_{s+2})
//   2. 16 x-MFMAs (reg operands; C-in = persistent zero quad) -> accOUT
//      -- their issue covers the Ah ds_read latency
//   3. h-MFMAs kk0-2 (24)
//   4. kk3 block interleaved with combine slices (SBAR-fenced):
//      {n0,n1|zi} {n2,n3|zf,iv} {n4,n5|zg,fv} {n6,n7|zo,gv}
//      -- combine VALU fills MFMA pipe-stall issue slots
//   5. ov, c, h; ring writes; ONE barrier.
// Arithmetic identical to R14 (same ops/association; scheduling only) ->
// bit-identical output expected (absmax 4.882812e-04).
// Ring audit as R14: Hbuf parity disjoint; Xbuf write@s read@s+1; prologue
// barrier protects Xbuf[0] WAR; barrier lgkmcnt drain orders frag reads.

#define LSTM_B 256
#define LSTM_S 4096
#define LSTM_D 64
#define LSTM_H 128
#define LSTM_G 512

typedef _Float16 f16x8 __attribute__((ext_vector_type(8)));
typedef float f32x4 __attribute__((ext_vector_type(4)));

#define SBAR() __builtin_amdgcn_sched_barrier(0)

__device__ __forceinline__ float sigm(float z) {
  return __builtin_amdgcn_rcpf(1.0f + __builtin_amdgcn_exp2f(-1.44269504f * z));
}
__device__ __forceinline__ float tanh_(float z) {
  return 1.0f - 2.0f * __builtin_amdgcn_rcpf(1.0f + __builtin_amdgcn_exp2f(2.88539008f * z));
}

__global__ __launch_bounds__(256, 1)
void lstm_mfma_kernel(const float* __restrict__ x,
                      const float* __restrict__ Wi,
                      const float* __restrict__ Wh,
                      const float* __restrict__ bh,
                      const float* __restrict__ Wo,
                      const float* __restrict__ bo,
                      float* __restrict__ out) {
  const int t    = threadIdx.x;      // 0..255
  const int lane = t & 63;
  const int w    = t >> 6;           // wave 0..3
  const int b    = blockIdx.x;
  const int lmod = lane & 15;        // row (A) / col (B) index within tile
  const int lgrp = lane >> 4;        // k-group 0..3

  __shared__ __align__(16) _Float16 Hbuf[2][LSTM_H];  // h ring
  __shared__ __align__(16) _Float16 Xbuf[2][LSTM_D];  // x ring (lead 2)
  __shared__ __align__(16) _Float16 Zr[8];            // zero region (16B)
  __shared__ float R[LSTM_H];                         // final reduce

  // ---- stage B fragments: nt = 2g+hh -> cols n = 128g + 32w + 16hh + lmod
  f16x8 Bf[8][6];
  #pragma unroll
  for (int g = 0; g < 4; ++g) {
    #pragma unroll
    for (int hh = 0; hh < 2; ++hh) {
      const int nt = 2 * g + hh;
      const int n = 128 * g + 32 * w + 16 * hh + lmod;
      #pragma unroll
      for (int kk = 0; kk < 6; ++kk) {
        union { f16x8 v; _Float16 e[8]; } uB;
        #pragma unroll
        for (int j = 0; j < 8; ++j) {
          const int k = 32 * kk + 8 * lgrp + j;
          const float val = (k < LSTM_H) ? Wh[(size_t)k * LSTM_G + n]
                                         : Wi[(size_t)(k - LSTM_H) * LSTM_G + n];
          uB.e[j] = (_Float16)val;
        }
        Bf[nt][kk] = uB.v;
      }
    }
  }

  const int ul = 32 * w + (lane & 31);
  const float bb0 = bh[ul];
  const float bb1 = bh[LSTM_H + ul];
  const float bb2 = bh[2 * LSTM_H + ul];
  const float bb3 = bh[3 * LSTM_H + ul];

  const float* xb = x + (size_t)b * (LSTM_S * LSTM_D);
  const bool areal = (lmod == 0) || (lmod == 4);

  // persistent zero quad: C-in of the first x-MFMA; NEVER written.
  const f32x4 ZQ = {0.f, 0.f, 0.f, 0.f};

  // ---- prologue: x_0 -> Xbuf[0], x_1 -> Xbuf[1], h_0 = 0 ----
  if (t < LSTM_H) Hbuf[0][t] = (_Float16)0.0f;
  if (w == 1) Xbuf[0][lane] = (_Float16)xb[lane];
  if (w == 2) Xbuf[1][lane] = (_Float16)xb[LSTM_D + lane];
  if (t < 8) Zr[t] = (_Float16)0.0f;
  __syncthreads();

  f16x8 X0a, X0b, X1a, X1b;
  f32x4 accP[8], accQ[8];
  {
    const char* a0 = areal ? ((const char*)&Xbuf[0][0] + 16 * lgrp)
                           : (const char*)&Zr[0];
    const int s0 = areal ? 64 : 0;
    f16x8 T0 = *(const f16x8*)(a0);
    f16x8 T1 = *(const f16x8*)(a0 + s0);
    const char* a1 = areal ? ((const char*)&Xbuf[1][0] + 16 * lgrp)
                           : (const char*)&Zr[0];
    X0a = *(const f16x8*)(a1);
    X0b = *(const f16x8*)(a1 + s0);
    #pragma unroll
    for (int n = 0; n < 8; ++n) {
      accP[n] = __builtin_amdgcn_mfma_f32_16x16x32_f16(T0, Bf[n][4], ZQ, 0, 0, 0);
      accP[n] = __builtin_amdgcn_mfma_f32_16x16x32_f16(T1, Bf[n][5], accP[n], 0, 0, 0);
    }
  }
  __syncthreads();                  // Xbuf[0] frags consumed; safe to rewrite
  if (w == 1) Xbuf[0][lane] = (_Float16)xb[2 * LSTM_D + lane];   // x_2
  float xA = 0.f, xB = 0.f;         // loop-top: xA = x_{s+3}, xB = x_{s+4}
  if (w == 3) {
    xA = xb[3 * LSTM_D + lane];
    xB = xb[4 * LSTM_D + lane];
  }
  float c = 0.f, hval = 0.f;
  __syncthreads();

  #define MFM(A_, B_, C_) __builtin_amdgcn_mfma_f32_16x16x32_f16(A_, B_, C_, 0, 0, 0)

  // one LSTM step (see header). P: parity. ACCIN: x-part of z_s (C-in);
  // ACCOUT: x-part of z_{s+1}. XC*: frags x_{s+1} (regs). XN*: frags x_{s+2}.
  #define STEPB(P, ACCIN, ACCOUT, XC0, XC1, XN0, XN1)                          \
  {                                                                            \
    float xn = 0.f;                                                            \
    if (w == 3) {                                                              \
      int si = s + 5; if (si > LSTM_S - 1) si = LSTM_S - 1;                    \
      xn = xb[(size_t)si * LSTM_D + lane];                                     \
    }                                                                          \
    const char* ahB = areal ? ((const char*)&Hbuf[P][0] + 16 * lgrp)           \
                            : (const char*)&Zr[0];                             \
    const int ahS = areal ? 64 : 0;                                            \
    f16x8 Ah0 = *(const f16x8*)(ahB);                                          \
    f16x8 Ah1 = *(const f16x8*)(ahB + 1 * ahS);                                \
    f16x8 Ah2 = *(const f16x8*)(ahB + 2 * ahS);                                \
    f16x8 Ah3 = *(const f16x8*)(ahB + 3 * ahS);                                \
    const char* axB = areal ? ((const char*)&Xbuf[P][0] + 16 * lgrp)           \
                            : (const char*)&Zr[0];                             \
    XN0 = *(const f16x8*)(axB);                                                \
    XN1 = *(const f16x8*)(axB + ahS);                                          \
    SBAR();                                                                    \
    _Pragma("unroll")                                                          \
    for (int n = 0; n < 8; ++n)                                                \
      ACCOUT[n] = MFM(XC0, Bf[n][4], ZQ);                                      \
    _Pragma("unroll")                                                          \
    for (int n = 0; n < 8; ++n)                                                \
      ACCOUT[n] = MFM(XC1, Bf[n][5], ACCOUT[n]);                               \
    SBAR();                                                                    \
    _Pragma("unroll")                                                          \
    for (int n = 0; n < 8; ++n)                                                \
      ACCIN[n] = MFM(Ah0, Bf[n][0], ACCIN[n]);                                 \
    _Pragma("unroll")                                                          \
    for (int n = 0; n < 8; ++n)                                                \
      ACCIN[n] = MFM(Ah1, Bf[n][1], ACCIN[n]);                                 \
    _Pragma("unroll")                                                          \
    for (int n = 0; n < 8; ++n)                                                \
      ACCIN[n] = MFM(Ah2, Bf[n][2], ACCIN[n]);                                 \
    SBAR();                                                                    \
    const bool hsel = (lane & 16) != 0;                                        \
    float zi, zf, zg, zo, iv, fv, gv, ov;                                      \
    /* kk3 block interleaved with combine slices */                            \
    ACCIN[0] = MFM(Ah3, Bf[0][3], ACCIN[0]);                                   \
    ACCIN[1] = MFM(Ah3, Bf[1][3], ACCIN[1]);                                   \
    SBAR();                                                                    \
    zi = (hsel ? ACCIN[1][0] : ACCIN[0][0]) + bb0;                             \
    SBAR();                                                                    \
    ACCIN[2] = MFM(Ah3, Bf[2][3], ACCIN[2]);                                   \
    ACCIN[3] = MFM(Ah3, Bf[3][3], ACCIN[3]);                                   \
    SBAR();                                                                    \
    zf = (hsel ? ACCIN[3][0] : ACCIN[2][0]) + bb1;                             \
    iv = sigm(zi);                                                             \
    SBAR();                                                                    \
    ACCIN[4] = MFM(Ah3, Bf[4][3], ACCIN[4]);                                   \
    ACCIN[5] = MFM(Ah3, Bf[5][3], ACCIN[5]);                                   \
    SBAR();                                                                    \
    zg = (hsel ? ACCIN[5][0] : ACCIN[4][0]) + bb2;                             \
    fv = sigm(zf);                                                             \
    SBAR();                                                                    \
    ACCIN[6] = MFM(Ah3, Bf[6][3], ACCIN[6]);                                   \
    ACCIN[7] = MFM(Ah3, Bf[7][3], ACCIN[7]);                                   \
    SBAR();                                                                    \
    zo = (hsel ? ACCIN[7][0] : ACCIN[6][0]) + bb3;                             \
    gv = tanh_(zg);                                                            \
    SBAR();                                                                    \
    ov = sigm(zo);                                                             \
    c = fv * c + iv * gv;                                                      \
    hval = ov * tanh_(c);                                                      \
    if (lane < 32) Hbuf[(P) ^ 1][ul] = (_Float16)hval;                         \
    if (w == 3) {                                                              \
      Xbuf[(P) ^ 1][lane] = (_Float16)xA;                                      \
      xA = xB;                                                                 \
      xB = xn;                                                                 \
    }                                                                          \
    __syncthreads();                                                           \
  }

  for (int s = 0; s < LSTM_S; s += 2) {
    STEPB(0, accP, accQ, X0a, X0b, X1a, X1b)
    ++s;
    STEPB(1, accQ, accP, X1a, X1b, X0a, X0b)
    --s;
  }
  #undef STEPB
  #undef MFM

  // ---- output: out[b] = h_last @ Wo + bo ----
  if (lane < 32) R[ul] = hval * Wo[ul];
  __syncthreads();
  if (t < 64) {
    float v = R[t] + R[t + 64];
    #pragma unroll
    for (int off = 32; off; off >>= 1) v += __shfl_down(v, off);
    if (t == 0) out[b] = v + bo[0];
  }
}

extern "C" void kernel_launch(void* const* d_in, const int* in_sizes, int n_in,
                              void* d_out, int out_size, void* d_ws, size_t ws_size,
                              hipStream_t stream) {
  const float* x  = (const float*)d_in[0];
  const float* Wi = (const float*)d_in[1];
  const float* Wh = (const float*)d_in[2];
  const float* bh = (const float*)d_in[3];
  const float* Wo = (const float*)d_in[4];
  const float* bo = (const float*)d_in[5];
  float* out = (float*)d_out;

  lstm_mfma_kernel<<<LSTM_B, 256, 0, stream>>>(x, Wi, Wh, bh, Wo, bo, out);
}

// Round 16
// 2279.896 us; speedup vs baseline: 1.0217x; 1.0217x over previous
//
#include <hip/hip_runtime.h>
#include <hip/hip_fp16.h>

// LSTM: B=256, S=4096, D=64, H=128 (4H=512 gate cols [i|f|g|o]), K=192=[h;x].
// One batch element per block (256 blocks = 1/CU), 512 threads = 8 waves
// (2 waves/SIMD — TLP covers the combine/barrier tail: while wave A is in
// its combine, wave B's MFMA stream keeps the matrix pipe fed).
// Wave w owns gates g=0..3 of units [16w,16w+16): n-tile nt=g, cols
// n = 128g + 16w + lmod. Per wave: 8 x-MFMA + 16 h-MFMA = 24 (48/SIMD,
// same pipe floor as R14). A = hx in row 0 (areal = lmod==0); lanes 0-15
// hold all 4 gates of unit u=16w+lane in reg 0 -> in-register combine.
// R14 techniques ported: x-MFMAs first (cover h ds_read), reg x-frags,
// ZQ C-in (no zero-init movs), depth-4 h-chains with accX C-in, lead-2
// Xbuf ring, ONE barrier/step. Per-column association identical to R14
// -> bit-identical output (absmax 4.882812e-04).
// Ring audit (as R14): Hbuf parity disjoint RAW/WAR across the barrier;
// Xbuf write@s -> read@s+1; prologue barrier protects Xbuf[0] WAR.

#define LSTM_B 256
#define LSTM_S 4096
#define LSTM_D 64
#define LSTM_H 128
#define LSTM_G 512

typedef _Float16 f16x8 __attribute__((ext_vector_type(8)));
typedef float f32x4 __attribute__((ext_vector_type(4)));

#define SBAR() __builtin_amdgcn_sched_barrier(0)

__device__ __forceinline__ float sigm(float z) {
  return __builtin_amdgcn_rcpf(1.0f + __builtin_amdgcn_exp2f(-1.44269504f * z));
}
__device__ __forceinline__ float tanh_(float z) {
  return 1.0f - 2.0f * __builtin_amdgcn_rcpf(1.0f + __builtin_amdgcn_exp2f(2.88539008f * z));
}

__global__ __launch_bounds__(512, 2)
void lstm_mfma_kernel(const float* __restrict__ x,
                      const float* __restrict__ Wi,
                      const float* __restrict__ Wh,
                      const float* __restrict__ bh,
                      const float* __restrict__ Wo,
                      const float* __restrict__ bo,
                      float* __restrict__ out) {
  const int t    = threadIdx.x;      // 0..511
  const int lane = t & 63;
  const int w    = t >> 6;           // wave 0..7
  const int b    = blockIdx.x;
  const int lmod = lane & 15;        // row (A) / col (B) index within tile
  const int lgrp = lane >> 4;        // k-group 0..3

  __shared__ __align__(16) _Float16 Hbuf[2][LSTM_H];  // h ring
  __shared__ __align__(16) _Float16 Xbuf[2][LSTM_D];  // x ring (lead 2)
  __shared__ __align__(16) _Float16 Zr[8];            // zero region (16B)
  __shared__ float R[LSTM_H];                         // final reduce

  // ---- stage B fragments: wave w, gate g -> cols n = 128g + 16w + lmod ----
  // elem j of Bf[g][kk] = W[k][n], k = 32*kk + 8*lgrp + j (same map as A)
  f16x8 Bf[4][6];
  #pragma unroll
  for (int g = 0; g < 4; ++g) {
    const int n = 128 * g + 16 * w + lmod;
    #pragma unroll
    for (int kk = 0; kk < 6; ++kk) {
      union { f16x8 v; _Float16 e[8]; } uB;
      #pragma unroll
      for (int j = 0; j < 8; ++j) {
        const int k = 32 * kk + 8 * lgrp + j;
        const float val = (k < LSTM_H) ? Wh[(size_t)k * LSTM_G + n]
                                       : Wi[(size_t)(k - LSTM_H) * LSTM_G + n];
        uB.e[j] = (_Float16)val;
      }
      Bf[g][kk] = uB.v;
    }
  }

  const int ul = 16 * w + lmod;      // this lane's unit (valid for lane<16)
  const float bb0 = bh[ul];
  const float bb1 = bh[LSTM_H + ul];
  const float bb2 = bh[2 * LSTM_H + ul];
  const float bb3 = bh[3 * LSTM_H + ul];

  const float* xb = x + (size_t)b * (LSTM_S * LSTM_D);
  const bool areal = (lmod == 0);    // A row 0 carries the batch row

  // persistent zero quad: C-in of the first x-MFMA; NEVER written.
  const f32x4 ZQ = {0.f, 0.f, 0.f, 0.f};

  // ---- prologue: x_0 -> Xbuf[0], x_1 -> Xbuf[1], h_0 = 0 ----
  if (t < LSTM_H) Hbuf[0][t] = (_Float16)0.0f;
  if (w == 1) Xbuf[0][lane] = (_Float16)xb[lane];
  if (w == 2) Xbuf[1][lane] = (_Float16)xb[LSTM_D + lane];
  if (t < 8) Zr[t] = (_Float16)0.0f;
  __syncthreads();

  f16x8 X0a, X0b, X1a, X1b;
  f32x4 accP[4], accQ[4];
  {
    const char* a0 = areal ? ((const char*)&Xbuf[0][0] + 16 * lgrp)
                           : (const char*)&Zr[0];
    const int s0 = areal ? 64 : 0;
    f16x8 T0 = *(const f16x8*)(a0);
    f16x8 T1 = *(const f16x8*)(a0 + s0);
    const char* a1 = areal ? ((const char*)&Xbuf[1][0] + 16 * lgrp)
                           : (const char*)&Zr[0];
    X0a = *(const f16x8*)(a1);
    X0b = *(const f16x8*)(a1 + s0);
    #pragma unroll
    for (int g = 0; g < 4; ++g) {
      accP[g] = __builtin_amdgcn_mfma_f32_16x16x32_f16(T0, Bf[g][4], ZQ, 0, 0, 0);
      accP[g] = __builtin_amdgcn_mfma_f32_16x16x32_f16(T1, Bf[g][5], accP[g], 0, 0, 0);
    }
  }
  __syncthreads();                  // Xbuf[0] frags consumed; safe to rewrite
  if (w == 1) Xbuf[0][lane] = (_Float16)xb[2 * LSTM_D + lane];   // x_2
  float xA = 0.f, xB = 0.f;         // loop-top: xA = x_{s+3}, xB = x_{s+4}
  if (w == 7) {
    xA = xb[3 * LSTM_D + lane];
    xB = xb[4 * LSTM_D + lane];
  }
  float c = 0.f, hval = 0.f;
  __syncthreads();

  #define MFM(A_, B_, C_) __builtin_amdgcn_mfma_f32_16x16x32_f16(A_, B_, C_, 0, 0, 0)

  // one step. P: parity. ACCIN: x-part of z_s (C-in); ACCOUT: x-part of
  // z_{s+1}. XC*: frags x_{s+1} (regs). XN*: frags x_{s+2} (read this step).
  #define STEPB(P, ACCIN, ACCOUT, XC0, XC1, XN0, XN1)                          \
  {                                                                            \
    float xn = 0.f;                                                            \
    if (w == 7) {                                                              \
      int si = s + 5; if (si > LSTM_S - 1) si = LSTM_S - 1;                    \
      xn = xb[(size_t)si * LSTM_D + lane];                                     \
    }                                                                          \
    const char* ahB = areal ? ((const char*)&Hbuf[P][0] + 16 * lgrp)           \
                            : (const char*)&Zr[0];                             \
    const int ahS = areal ? 64 : 0;                                            \
    f16x8 Ah0 = *(const f16x8*)(ahB);                                          \
    f16x8 Ah1 = *(const f16x8*)(ahB + 1 * ahS);                                \
    f16x8 Ah2 = *(const f16x8*)(ahB + 2 * ahS);                                \
    f16x8 Ah3 = *(const f16x8*)(ahB + 3 * ahS);                                \
    const char* axB = areal ? ((const char*)&Xbuf[P][0] + 16 * lgrp)           \
                            : (const char*)&Zr[0];                             \
    XN0 = *(const f16x8*)(axB);                                                \
    XN1 = *(const f16x8*)(axB + ahS);                                          \
    SBAR();                                                                    \
    _Pragma("unroll")                                                          \
    for (int g = 0; g < 4; ++g)                                                \
      ACCOUT[g] = MFM(XC0, Bf[g][4], ZQ);                                      \
    _Pragma("unroll")                                                          \
    for (int g = 0; g < 4; ++g)                                                \
      ACCOUT[g] = MFM(XC1, Bf[g][5], ACCOUT[g]);                               \
    SBAR();                                                                    \
    _Pragma("unroll")                                                          \
    for (int g = 0; g < 4; ++g)                                                \
      ACCIN[g] = MFM(Ah0, Bf[g][0], ACCIN[g]);                                 \
    _Pragma("unroll")                                                          \
    for (int g = 0; g < 4; ++g)                                                \
      ACCIN[g] = MFM(Ah1, Bf[g][1], ACCIN[g]);                                 \
    _Pragma("unroll")                                                          \
    for (int g = 0; g < 4; ++g)                                                \
      ACCIN[g] = MFM(Ah2, Bf[g][2], ACCIN[g]);                                 \
    _Pragma("unroll")                                                          \
    for (int g = 0; g < 4; ++g)                                                \
      ACCIN[g] = MFM(Ah3, Bf[g][3], ACCIN[g]);                                 \
    {                                                                          \
      const float zi = ACCIN[0][0] + bb0;                                      \
      const float zf = ACCIN[1][0] + bb1;                                      \
      const float zg = ACCIN[2][0] + bb2;                                      \
      const float zo = ACCIN[3][0] + bb3;                                      \
      const float iv = sigm(zi);                                               \
      const float fv = sigm(zf);                                               \
      const float gv = tanh_(zg);                                              \
      const float ov = sigm(zo);                                               \
      c = fv * c + iv * gv;                                                    \
      hval = ov * tanh_(c);                                                    \
      if (lane < 16) Hbuf[(P) ^ 1][ul] = (_Float16)hval;                       \
    }                                                                          \
    if (w == 7) {                                                              \
      Xbuf[(P) ^ 1][lane] = (_Float16)xA;                                      \
      xA = xB;                                                                 \
      xB = xn;                                                                 \
    }                                                                          \
    __syncthreads();                                                           \
  }

  for (int s = 0; s < LSTM_S; s += 2) {
    STEPB(0, accP, accQ, X0a, X0b, X1a, X1b)
    ++s;
    STEPB(1, accQ, accP, X1a, X1b, X0a, X0b)
    --s;
  }
  #undef STEPB
  #undef MFM

  // ---- output: out[b] = h_last @ Wo + bo ----
  if (lane < 16) R[ul] = hval * Wo[ul];
  __syncthreads();
  if (t < 64) {
    float v = R[t] + R[t + 64];
    #pragma unroll
    for (int off = 32; off; off >>= 1) v += __shfl_down(v, off);
    if (t == 0) out[b] = v + bo[0];
  }
}

extern "C" void kernel_launch(void* const* d_in, const int* in_sizes, int n_in,
                              void* d_out, int out_size, void* d_ws, size_t ws_size,
                              hipStream_t stream) {
  const float* x  = (const float*)d_in[0];
  const float* Wi = (const float*)d_in[1];
  const float* Wh = (const float*)d_in[2];
  const float* bh = (const float*)d_in[3];
  const float* Wo = (const float*)d_in[4];
  const float* bo = (const float*)d_in[5];
  float* out = (float*)d_out;

  lstm_mfma_kernel<<<LSTM_B, 512, 0, stream>>>(x, Wi, Wh, bh, Wo, bo, out);
}

// Round 17
// 2205.381 us; speedup vs baseline: 1.0562x; 1.0338x over previous
//
#include <hip/hip_runtime.h>
#include <hip/hip_fp16.h>

// LSTM: B=256, S=4096, D=64, H=128 (4H=512 gate cols [i|f|g|o]), K=192=[h;x].
// One batch element per block (256 blocks = 1/CU), 256 threads = 4 waves
// (1 wave/SIMD). z = [h;x] @ [Wh;Wi] via v_mfma_f32_16x16x32_f16, A rows 0+4
// carry the batch row (lanes 0-31 own one unit's gates).
// Schedule per step (R14 + late-x fill of the combine window):
//   1. ds_read Ah (h_s) + next-x frags (x_{s+2})
//   2. 8 x-MFMAs n=0..3 (reg operands, ZQ C-in) -> cover Ah ds_read latency
//   3. 32 h-MFMAs kk0-3 (8 chains depth 4, C-in = accIN x-part)
//   4. extract zi,zf -> 2 xM -> zg,zo -> 2 xM  (kk3 results >=4 issues old)
//   5. remaining 4 late x-MFMAs (n=4..7 kk5) interleaved with sigm/tanh
//      slices: 128 cyc of matrix issue runs concurrent with the ~150-cyc
//      trans chain (R15's mistake was filling with ops the combine DEPENDS on)
//   6. c/h chain, ring writes, ONE barrier.
// Same ops & association as R14 -> bit-identical output (4.882812e-04).
// Ring audit as R14: Hbuf parity disjoint; Xbuf write@s read@s+1; prologue
// barrier protects Xbuf[0] WAR; barrier lgkmcnt drain orders frag reads.

#define LSTM_B 256
#define LSTM_S 4096
#define LSTM_D 64
#define LSTM_H 128
#define LSTM_G 512

typedef _Float16 f16x8 __attribute__((ext_vector_type(8)));
typedef float f32x4 __attribute__((ext_vector_type(4)));

#define SBAR() __builtin_amdgcn_sched_barrier(0)

__device__ __forceinline__ float sigm(float z) {
  return __builtin_amdgcn_rcpf(1.0f + __builtin_amdgcn_exp2f(-1.44269504f * z));
}
__device__ __forceinline__ float tanh_(float z) {
  return 1.0f - 2.0f * __builtin_amdgcn_rcpf(1.0f + __builtin_amdgcn_exp2f(2.88539008f * z));
}

__global__ __launch_bounds__(256, 1)
void lstm_mfma_kernel(const float* __restrict__ x,
                      const float* __restrict__ Wi,
                      const float* __restrict__ Wh,
                      const float* __restrict__ bh,
                      const float* __restrict__ Wo,
                      const float* __restrict__ bo,
                      float* __restrict__ out) {
  const int t    = threadIdx.x;      // 0..255
  const int lane = t & 63;
  const int w    = t >> 6;           // wave 0..3
  const int b    = blockIdx.x;
  const int lmod = lane & 15;        // row (A) / col (B) index within tile
  const int lgrp = lane >> 4;        // k-group 0..3

  __shared__ __align__(16) _Float16 Hbuf[2][LSTM_H];  // h ring
  __shared__ __align__(16) _Float16 Xbuf[2][LSTM_D];  // x ring (lead 2)
  __shared__ __align__(16) _Float16 Zr[8];            // zero region (16B)
  __shared__ float R[LSTM_H];                         // final reduce

  // ---- stage B fragments: nt = 2g+hh -> cols n = 128g + 32w + 16hh + lmod
  f16x8 Bf[8][6];
  #pragma unroll
  for (int g = 0; g < 4; ++g) {
    #pragma unroll
    for (int hh = 0; hh < 2; ++hh) {
      const int nt = 2 * g + hh;
      const int n = 128 * g + 32 * w + 16 * hh + lmod;
      #pragma unroll
      for (int kk = 0; kk < 6; ++kk) {
        union { f16x8 v; _Float16 e[8]; } uB;
        #pragma unroll
        for (int j = 0; j < 8; ++j) {
          const int k = 32 * kk + 8 * lgrp + j;
          const float val = (k < LSTM_H) ? Wh[(size_t)k * LSTM_G + n]
                                         : Wi[(size_t)(k - LSTM_H) * LSTM_G + n];
          uB.e[j] = (_Float16)val;
        }
        Bf[nt][kk] = uB.v;
      }
    }
  }

  const int ul = 32 * w + (lane & 31);
  const float bb0 = bh[ul];
  const float bb1 = bh[LSTM_H + ul];
  const float bb2 = bh[2 * LSTM_H + ul];
  const float bb3 = bh[3 * LSTM_H + ul];

  const float* xb = x + (size_t)b * (LSTM_S * LSTM_D);
  const bool areal = (lmod == 0) || (lmod == 4);

  // persistent zero quad: C-in of the first x-MFMA; NEVER written.
  const f32x4 ZQ = {0.f, 0.f, 0.f, 0.f};

  // ---- prologue: x_0 -> Xbuf[0], x_1 -> Xbuf[1], h_0 = 0 ----
  if (t < LSTM_H) Hbuf[0][t] = (_Float16)0.0f;
  if (w == 1) Xbuf[0][lane] = (_Float16)xb[lane];
  if (w == 2) Xbuf[1][lane] = (_Float16)xb[LSTM_D + lane];
  if (t < 8) Zr[t] = (_Float16)0.0f;
  __syncthreads();

  f16x8 X0a, X0b, X1a, X1b;
  f32x4 accP[8], accQ[8];
  {
    const char* a0 = areal ? ((const char*)&Xbuf[0][0] + 16 * lgrp)
                           : (const char*)&Zr[0];
    const int s0 = areal ? 64 : 0;
    f16x8 T0 = *(const f16x8*)(a0);
    f16x8 T1 = *(const f16x8*)(a0 + s0);
    const char* a1 = areal ? ((const char*)&Xbuf[1][0] + 16 * lgrp)
                           : (const char*)&Zr[0];
    X0a = *(const f16x8*)(a1);
    X0b = *(const f16x8*)(a1 + s0);
    #pragma unroll
    for (int n = 0; n < 8; ++n) {
      accP[n] = __builtin_amdgcn_mfma_f32_16x16x32_f16(T0, Bf[n][4], ZQ, 0, 0, 0);
      accP[n] = __builtin_amdgcn_mfma_f32_16x16x32_f16(T1, Bf[n][5], accP[n], 0, 0, 0);
    }
  }
  __syncthreads();                  // Xbuf[0] frags consumed; safe to rewrite
  if (w == 1) Xbuf[0][lane] = (_Float16)xb[2 * LSTM_D + lane];   // x_2
  float xA = 0.f, xB = 0.f;         // loop-top: xA = x_{s+3}, xB = x_{s+4}
  if (w == 3) {
    xA = xb[3 * LSTM_D + lane];
    xB = xb[4 * LSTM_D + lane];
  }
  float c = 0.f, hval = 0.f;
  __syncthreads();

  #define MFM(A_, B_, C_) __builtin_amdgcn_mfma_f32_16x16x32_f16(A_, B_, C_, 0, 0, 0)

  // one step. P: parity. ACCIN: x-part of z_s (C-in); ACCOUT: x-part of
  // z_{s+1}. XC*: frags x_{s+1} (regs). XN*: frags x_{s+2} (read this step).
  #define STEPB(P, ACCIN, ACCOUT, XC0, XC1, XN0, XN1)                          \
  {                                                                            \
    float xn = 0.f;                                                            \
    if (w == 3) {                                                              \
      int si = s + 5; if (si > LSTM_S - 1) si = LSTM_S - 1;                    \
      xn = xb[(size_t)si * LSTM_D + lane];                                     \
    }                                                                          \
    const char* ahB = areal ? ((const char*)&Hbuf[P][0] + 16 * lgrp)           \
                            : (const char*)&Zr[0];                             \
    const int ahS = areal ? 64 : 0;                                            \
    f16x8 Ah0 = *(const f16x8*)(ahB);                                          \
    f16x8 Ah1 = *(const f16x8*)(ahB + 1 * ahS);                                \
    f16x8 Ah2 = *(const f16x8*)(ahB + 2 * ahS);                                \
    f16x8 Ah3 = *(const f16x8*)(ahB + 3 * ahS);                                \
    const char* axB = areal ? ((const char*)&Xbuf[P][0] + 16 * lgrp)           \
                            : (const char*)&Zr[0];                             \
    XN0 = *(const f16x8*)(axB);                                                \
    XN1 = *(const f16x8*)(axB + ahS);                                          \
    SBAR();                                                                    \
    /* early x-MFMAs n=0..3: cover Ah ds_read latency */                       \
    _Pragma("unroll")                                                          \
    for (int n = 0; n < 4; ++n)                                                \
      ACCOUT[n] = MFM(XC0, Bf[n][4], ZQ);                                      \
    _Pragma("unroll")                                                          \
    for (int n = 0; n < 4; ++n)                                                \
      ACCOUT[n] = MFM(XC1, Bf[n][5], ACCOUT[n]);                               \
    SBAR();                                                                    \
    /* h-MFMAs: 8 chains depth 4 */                                            \
    _Pragma("unroll")                                                          \
    for (int n = 0; n < 8; ++n)                                                \
      ACCIN[n] = MFM(Ah0, Bf[n][0], ACCIN[n]);                                 \
    _Pragma("unroll")                                                          \
    for (int n = 0; n < 8; ++n)                                                \
      ACCIN[n] = MFM(Ah1, Bf[n][1], ACCIN[n]);                                 \
    _Pragma("unroll")                                                          \
    for (int n = 0; n < 8; ++n)                                                \
      ACCIN[n] = MFM(Ah2, Bf[n][2], ACCIN[n]);                                 \
    _Pragma("unroll")                                                          \
    for (int n = 0; n < 8; ++n)                                                \
      ACCIN[n] = MFM(Ah3, Bf[n][3], ACCIN[n]);                                 \
    SBAR();                                                                    \
    const bool hsel = (lane & 16) != 0;                                        \
    float zi, zf, zg, zo, iv, fv, gv, ov;                                      \
    /* extraction + late x-MFMAs interleaved with combine slices */            \
    zi = (hsel ? ACCIN[1][0] : ACCIN[0][0]) + bb0;                             \
    zf = (hsel ? ACCIN[3][0] : ACCIN[2][0]) + bb1;                             \
    SBAR();                                                                    \
    ACCOUT[4] = MFM(XC0, Bf[4][4], ZQ);                                        \
    ACCOUT[5] = MFM(XC0, Bf[5][4], ZQ);                                        \
    SBAR();                                                                    \
    zg = (hsel ? ACCIN[5][0] : ACCIN[4][0]) + bb2;                             \
    zo = (hsel ? ACCIN[7][0] : ACCIN[6][0]) + bb3;                             \
    SBAR();                                                                    \
    ACCOUT[6] = MFM(XC0, Bf[6][4], ZQ);                                        \
    ACCOUT[7] = MFM(XC0, Bf[7][4], ZQ);                                        \
    SBAR();                                                                    \
    iv = sigm(zi);                                                             \
    SBAR();                                                                    \
    ACCOUT[4] = MFM(XC1, Bf[4][5], ACCOUT[4]);                                 \
    ACCOUT[5] = MFM(XC1, Bf[5][5], ACCOUT[5]);                                 \
    SBAR();                                                                    \
    fv = sigm(zf);                                                             \
    gv = tanh_(zg);                                                            \
    SBAR();                                                                    \
    ACCOUT[6] = MFM(XC1, Bf[6][5], ACCOUT[6]);                                 \
    ACCOUT[7] = MFM(XC1, Bf[7][5], ACCOUT[7]);                                 \
    SBAR();                                                                    \
    ov = sigm(zo);                                                             \
    c = fv * c + iv * gv;                                                      \
    hval = ov * tanh_(c);                                                      \
    if (lane < 32) Hbuf[(P) ^ 1][ul] = (_Float16)hval;                         \
    if (w == 3) {                                                              \
      Xbuf[(P) ^ 1][lane] = (_Float16)xA;                                      \
      xA = xB;                                                                 \
      xB = xn;                                                                 \
    }                                                                          \
    __syncthreads();                                                           \
  }

  for (int s = 0; s < LSTM_S; s += 2) {
    STEPB(0, accP, accQ, X0a, X0b, X1a, X1b)
    ++s;
    STEPB(1, accQ, accP, X1a, X1b, X0a, X0b)
    --s;
  }
  #undef STEPB
  #undef MFM

  // ---- output: out[b] = h_last @ Wo + bo ----
  if (lane < 32) R[ul] = hval * Wo[ul];
  __syncthreads();
  if (t < 64) {
    float v = R[t] + R[t + 64];
    #pragma unroll
    for (int off = 32; off; off >>= 1) v += __shfl_down(v, off);
    if (t == 0) out[b] = v + bo[0];
  }
}

extern "C" void kernel_launch(void* const* d_in, const int* in_sizes, int n_in,
                              void* d_out, int out_size, void* d_ws, size_t ws_size,
                              hipStream_t stream) {
  const float* x  = (const float*)d_in[0];
  const float* Wi = (const float*)d_in[1];
  const float* Wh = (const float*)d_in[2];
  const float* bh = (const float*)d_in[3];
  const float* Wo = (const float*)d_in[4];
  const float* bo = (const float*)d_in[5];
  float* out = (float*)d_out;

  lstm_mfma_kernel<<<LSTM_B, 256, 0, stream>>>(x, Wi, Wh, bh, Wo, bo, out);
}

// Round 18
// 1822.325 us; speedup vs baseline: 1.2783x; 1.2102x over previous
//
#include <hip/hip_runtime.h>
#include <hip/hip_fp16.h>

// LSTM: B=256, S=4096, D=64, H=128 (4H=512 gate cols [i|f|g|o]).
// One batch element per block (256 blocks = 1/CU), 256 threads = 4 waves.
// NEW vs R17: the x-projection xg = x@Wi is hoisted OUT of the recurrence
// into a chunked look-ahead GEMM (full 16-row A utilization: 16 timesteps
// per MFMA). Per step only the h-part runs: 32 MFMA/SIMD (pipe floor 768
// -> ~512 cyc). Combine adds xg as a scalar from LDS.
//   XGb[2][32][512] fp32 (128 KB, dynamic LDS): chunk c steps read buf c&1;
//   at sc==0 of chunk c a one-shot 32-MFMA GEMM writes chunk c+1 -> buf
//   (c+1)&1 (last reader was chunk c-1, >=1 barrier ago). A-frags (x rows of
//   chunk c+2) are global-loaded at sc==16, cvt at the next chunk top
//   (16-step latency window). Last chunks clamp rows / write dead buffer.
// h-part layout as R14-R17: A rows 0+4 duplicate the batch row, lanes 0-31
// own one unit's gates, combine in-register; Hbuf parity ring, ONE barrier.
// z = (h-chain from ZQ) + xg + bias — reassociation vs R17 is ~ulp.

#define LSTM_B 256
#define LSTM_S 4096
#define LSTM_D 64
#define LSTM_H 128
#define LSTM_G 512
#define CHS 32
#define SMEM_BYTES (131072 + 512 + 16 + 512)

typedef _Float16 f16x8 __attribute__((ext_vector_type(8)));
typedef float f32x4 __attribute__((ext_vector_type(4)));

#define SBAR() __builtin_amdgcn_sched_barrier(0)
#define MFM(A_, B_, C_) __builtin_amdgcn_mfma_f32_16x16x32_f16(A_, B_, C_, 0, 0, 0)

__device__ __forceinline__ float sigm(float z) {
  return __builtin_amdgcn_rcpf(1.0f + __builtin_amdgcn_exp2f(-1.44269504f * z));
}
__device__ __forceinline__ float tanh_(float z) {
  return 1.0f - 2.0f * __builtin_amdgcn_rcpf(1.0f + __builtin_amdgcn_exp2f(2.88539008f * z));
}
__device__ __forceinline__ f16x8 cvt8(float4 lo, float4 hi) {
  f16x8 r;
  r[0] = (_Float16)lo.x; r[1] = (_Float16)lo.y; r[2] = (_Float16)lo.z; r[3] = (_Float16)lo.w;
  r[4] = (_Float16)hi.x; r[5] = (_Float16)hi.y; r[6] = (_Float16)hi.z; r[7] = (_Float16)hi.w;
  return r;
}

__global__ __launch_bounds__(256, 1)
void lstm_mfma_kernel(const float* __restrict__ x,
                      const float* __restrict__ Wi,
                      const float* __restrict__ Wh,
                      const float* __restrict__ bh,
                      const float* __restrict__ Wo,
                      const float* __restrict__ bo,
                      float* __restrict__ out) {
  const int t    = threadIdx.x;      // 0..255
  const int lane = t & 63;
  const int w    = t >> 6;           // wave 0..3
  const int b    = blockIdx.x;
  const int lmod = lane & 15;
  const int lgrp = lane >> 4;

  extern __shared__ char smem[];
  float*    XGb = (float*)smem;                        // [2][CHS][512] fp32
  _Float16* Hb  = (_Float16*)(smem + 131072);          // [2][128]
  _Float16* Zr  = (_Float16*)(smem + 131072 + 512);    // [8] zero region
  float*    Rr  = (float*)(smem + 131072 + 512 + 16);  // [128] reduce

  // ---- B fragments: nt = 2g+hh -> cols n = 128g + 32w + 16hh + lmod ----
  // Bf (Wh, kk0..3) and Bfx (Wi, kk0..1); elem j -> k = 32kk + 8lgrp + j.
  f16x8 Bf[8][4], Bfx[8][2];
  #pragma unroll
  for (int g = 0; g < 4; ++g) {
    #pragma unroll
    for (int hh = 0; hh < 2; ++hh) {
      const int nt = 2 * g + hh;
      const int n = 128 * g + 32 * w + 16 * hh + lmod;
      #pragma unroll
      for (int kk = 0; kk < 4; ++kk) {
        union { f16x8 v; _Float16 e[8]; } u;
        #pragma unroll
        for (int j = 0; j < 8; ++j)
          u.e[j] = (_Float16)Wh[(size_t)(32 * kk + 8 * lgrp + j) * LSTM_G + n];
        Bf[nt][kk] = u.v;
      }
      #pragma unroll
      for (int kk = 0; kk < 2; ++kk) {
        union { f16x8 v; _Float16 e[8]; } u;
        #pragma unroll
        for (int j = 0; j < 8; ++j)
          u.e[j] = (_Float16)Wi[(size_t)(32 * kk + 8 * lgrp + j) * LSTM_G + n];
        Bfx[nt][kk] = u.v;
      }
    }
  }

  const int ul = 32 * w + (lane & 31);
  const float bb0 = bh[ul];
  const float bb1 = bh[LSTM_H + ul];
  const float bb2 = bh[2 * LSTM_H + ul];
  const float bb3 = bh[3 * LSTM_H + ul];

  const float* xb = x + (size_t)b * (LSTM_S * LSTM_D);
  const bool areal = (lmod == 0) || (lmod == 4);
  const f32x4 ZQ = {0.f, 0.f, 0.f, 0.f};

  if (t < LSTM_H) Hb[t] = (_Float16)0.0f;    // Hb[0][*] = h_0 = 0
  if (t < 8) Zr[t] = (_Float16)0.0f;

  #define XLOAD(DA, DB, ROW, KK)                                          \
    { const float* p_ = xb + (size_t)(ROW) * LSTM_D + 32 * (KK) + 8 * lgrp; \
      DA = *(const float4*)p_; DB = *(const float4*)(p_ + 4); }

  float4 xf00a, xf00b, xf01a, xf01b, xf10a, xf10b, xf11a, xf11b;

  // ---- prologue: chunk-0 XG (x rows 0..31) -> XGb[0]; preload chunk-1 frags
  {
    XLOAD(xf00a, xf00b, lmod, 0)      XLOAD(xf01a, xf01b, lmod, 1)
    XLOAD(xf10a, xf10b, 16 + lmod, 0) XLOAD(xf11a, xf11b, 16 + lmod, 1)
    f16x8 A00 = cvt8(xf00a, xf00b), A01 = cvt8(xf01a, xf01b);
    f16x8 A10 = cvt8(xf10a, xf10b), A11 = cvt8(xf11a, xf11b);
    #pragma unroll
    for (int nt = 0; nt < 8; ++nt) {
      f32x4 t0 = MFM(A00, Bfx[nt][0], ZQ); t0 = MFM(A01, Bfx[nt][1], t0);
      f32x4 t1 = MFM(A10, Bfx[nt][0], ZQ); t1 = MFM(A11, Bfx[nt][1], t1);
      const int nc = 128 * (nt >> 1) + 32 * w + 16 * (nt & 1) + lmod;
      #pragma unroll
      for (int r = 0; r < 4; ++r) {
        XGb[(4 * lgrp + r) * 512 + nc]        = t0[r];   // rows 0..15
        XGb[(16 + 4 * lgrp + r) * 512 + nc]   = t1[r];   // rows 16..31
      }
    }
    XLOAD(xf00a, xf00b, 32 + lmod, 0) XLOAD(xf01a, xf01b, 32 + lmod, 1)
    XLOAD(xf10a, xf10b, 48 + lmod, 0) XLOAD(xf11a, xf11b, 48 + lmod, 1)
  }
  float c = 0.f, hval = 0.f;
  __syncthreads();

  // one step. P = s&1 (Hbuf parity). sc = s&31, cb = (s>>5)&1.
  #define STEPB(P)                                                            \
  {                                                                           \
    const int sc = s & (CHS - 1);                                             \
    const int cb = (s >> 5) & 1;                                              \
    const float* xgrow = XGb + cb * (CHS * 512) + sc * 512;                   \
    const float xgi = xgrow[ul];                                              \
    const float xgf = xgrow[LSTM_H + ul];                                     \
    const float xgg = xgrow[2 * LSTM_H + ul];                                 \
    const float xgo = xgrow[3 * LSTM_H + ul];                                 \
    const char* ahB = areal ? ((const char*)(Hb + (P) * LSTM_H) + 16 * lgrp)  \
                            : (const char*)Zr;                                \
    const int ahS = areal ? 64 : 0;                                           \
    f16x8 Ah0 = *(const f16x8*)(ahB);                                         \
    f16x8 Ah1 = *(const f16x8*)(ahB + 1 * ahS);                               \
    f16x8 Ah2 = *(const f16x8*)(ahB + 2 * ahS);                               \
    f16x8 Ah3 = *(const f16x8*)(ahB + 3 * ahS);                               \
    SBAR();                                                                   \
    if (sc == 16) {  /* load x rows of chunk c+2 (used at next chunk top) */  \
      const int rb = ((s >> 5) + 2) * CHS;                                    \
      int r0 = rb + lmod;      if (r0 > LSTM_S - 1) r0 = LSTM_S - 1;          \
      int r1 = rb + 16 + lmod; if (r1 > LSTM_S - 1) r1 = LSTM_S - 1;          \
      XLOAD(xf00a, xf00b, r0, 0) XLOAD(xf01a, xf01b, r0, 1)                   \
      XLOAD(xf10a, xf10b, r1, 0) XLOAD(xf11a, xf11b, r1, 1)                   \
    }                                                                         \
    if (sc == 0) {   /* one-shot GEMM: XG of chunk c+1 -> buf (c+1)&1 */      \
      const int nb = ((s >> 5) + 1) & 1;                                      \
      f16x8 A00 = cvt8(xf00a, xf00b), A01 = cvt8(xf01a, xf01b);               \
      f16x8 A10 = cvt8(xf10a, xf10b), A11 = cvt8(xf11a, xf11b);               \
      float* pb = XGb + nb * (CHS * 512);                                     \
      _Pragma("unroll")                                                       \
      for (int nt = 0; nt < 8; ++nt) {                                        \
        f32x4 t0 = MFM(A00, Bfx[nt][0], ZQ); t0 = MFM(A01, Bfx[nt][1], t0);   \
        f32x4 t1 = MFM(A10, Bfx[nt][0], ZQ); t1 = MFM(A11, Bfx[nt][1], t1);   \
        const int nc = 128 * (nt >> 1) + 32 * w + 16 * (nt & 1) + lmod;       \
        _Pragma("unroll")                                                     \
        for (int r = 0; r < 4; ++r) {                                         \
          pb[(4 * lgrp + r) * 512 + nc]      = t0[r];                         \
          pb[(16 + 4 * lgrp + r) * 512 + nc] = t1[r];                         \
        }                                                                     \
      }                                                                       \
    }                                                                         \
    SBAR();                                                                   \
    f32x4 accH[8];                                                            \
    _Pragma("unroll")                                                         \
    for (int n = 0; n < 8; ++n) accH[n] = MFM(Ah0, Bf[n][0], ZQ);             \
    _Pragma("unroll")                                                         \
    for (int n = 0; n < 8; ++n) accH[n] = MFM(Ah1, Bf[n][1], accH[n]);        \
    _Pragma("unroll")                                                         \
    for (int n = 0; n < 8; ++n) accH[n] = MFM(Ah2, Bf[n][2], accH[n]);        \
    _Pragma("unroll")                                                         \
    for (int n = 0; n < 8; ++n) accH[n] = MFM(Ah3, Bf[n][3], accH[n]);        \
    {                                                                         \
      const bool hsel = (lane & 16) != 0;                                     \
      const float zi = (hsel ? accH[1][0] : accH[0][0]) + xgi + bb0;          \
      const float zf = (hsel ? accH[3][0] : accH[2][0]) + xgf + bb1;          \
      const float zg = (hsel ? accH[5][0] : accH[4][0]) + xgg + bb2;          \
      const float zo = (hsel ? accH[7][0] : accH[6][0]) + xgo + bb3;          \
      const float iv = sigm(zi);                                              \
      const float fv = sigm(zf);                                              \
      const float gv = tanh_(zg);                                             \
      const float ov = sigm(zo);                                              \
      c = fv * c + iv * gv;                                                   \
      hval = ov * tanh_(c);                                                   \
      if (lane < 32) Hb[((P) ^ 1) * LSTM_H + ul] = (_Float16)hval;            \
    }                                                                         \
    __syncthreads();                                                          \
  }

  for (int s = 0; s < LSTM_S; s += 2) {
    STEPB(0)
    ++s;
    STEPB(1)
    --s;
  }
  #undef STEPB
  #undef XLOAD

  // ---- output: out[b] = h_last @ Wo + bo ----
  if (lane < 32) Rr[ul] = hval * Wo[ul];
  __syncthreads();
  if (t < 64) {
    float v = Rr[t] + Rr[t + 64];
    #pragma unroll
    for (int off = 32; off; off >>= 1) v += __shfl_down(v, off);
    if (t == 0) out[b] = v + bo[0];
  }
}

extern "C" void kernel_launch(void* const* d_in, const int* in_sizes, int n_in,
                              void* d_out, int out_size, void* d_ws, size_t ws_size,
                              hipStream_t stream) {
  const float* x  = (const float*)d_in[0];
  const float* Wi = (const float*)d_in[1];
  const float* Wh = (const float*)d_in[2];
  const float* bh = (const float*)d_in[3];
  const float* Wo = (const float*)d_in[4];
  const float* bo = (const float*)d_in[5];
  float* out = (float*)d_out;

  hipFuncSetAttribute((const void*)lstm_mfma_kernel,
                      hipFuncAttributeMaxDynamicSharedMemorySize, SMEM_BYTES);
  lstm_mfma_kernel<<<LSTM_B, 256, SMEM_BYTES, stream>>>(x, Wi, Wh, bh, Wo, bo, out);
}